// Round 11
// baseline (192.204 us; speedup 1.0000x reference)
//
#include <hip/hip_runtime.h>
#include <stdint.h>

#define NB 2
#define NT 4096
#define NC 768
#define NH 12
#define ND 64
#define NBT (NB*NT)      // 8192
#define NQKV (3*NC)      // 2304

typedef _Float16 half_t;
typedef __attribute__((ext_vector_type(8))) _Float16 f16x8;
typedef __attribute__((ext_vector_type(4))) _Float16 f16x4;
typedef __attribute__((ext_vector_type(2))) __fp16 fp16x2;   // native type of cvt_pkrtz
typedef __attribute__((ext_vector_type(4))) float f32x4;
typedef __attribute__((ext_vector_type(16))) float f32x16;

#define MFMA16(a,b,c) __builtin_amdgcn_mfma_f32_16x16x32_f16((a),(b),(c),0,0,0)
#define MFMA32(a,b,c) __builtin_amdgcn_mfma_f32_32x32x16_f16((a),(b),(c),0,0,0)

__device__ __forceinline__ void load_lds16(const void* g, void* l) {
    auto gp = reinterpret_cast<__attribute__((address_space(1))) char*>(reinterpret_cast<uintptr_t>(g));
    auto lp = reinterpret_cast<__attribute__((address_space(3))) char*>(reinterpret_cast<uintptr_t>(l));
    __builtin_amdgcn_global_load_lds(gp, lp, 16, 0, 0);
}

// ---------------- prep: fused {pack x fp32->f16} + {tiled transpose Wa} + {tiled transpose Wp} ----------------
#define PACK_BLKS ((NBT * NC / 4) / 256)          // 6144
#define WA_TILES ((NC / 32) * (NQKV / 32))        // 24*72 = 1728
#define WP_TILES ((NC / 32) * (NC / 32))          // 24*24 = 576
#define PREP_BLKS (PACK_BLKS + WA_TILES + WP_TILES)

__global__ __launch_bounds__(256) void k_prep(const float* __restrict__ x, half_t* __restrict__ xh,
                                              const float* __restrict__ Wa, half_t* __restrict__ Wat,
                                              const float* __restrict__ Wp, half_t* __restrict__ Wpt) {
    const int bid = blockIdx.x, tid = threadIdx.x;
    if (bid < PACK_BLKS) {
        const int i = bid * 256 + tid;
        float4 f = reinterpret_cast<const float4*>(x)[i];
        f16x4 h;
        h[0] = (half_t)f.x; h[1] = (half_t)f.y; h[2] = (half_t)f.z; h[3] = (half_t)f.w;
        reinterpret_cast<f16x4*>(xh)[i] = h;
        return;
    }
    __shared__ half_t tile[32][36];
    const float* in; half_t* out; int N, kt, nt;
    if (bid < PACK_BLKS + WA_TILES) {
        const int t = bid - PACK_BLKS;
        in = Wa; out = Wat; N = NQKV;
        kt = t / (NQKV / 32); nt = t - kt * (NQKV / 32);
    } else {
        const int t = bid - PACK_BLKS - WA_TILES;
        in = Wp; out = Wpt; N = NC;
        kt = t / (NC / 32); nt = t - kt * (NC / 32);
    }
    const int k0 = kt * 32, n0 = nt * 32;
    {
        const int r = tid >> 3, c = (tid & 7) * 4;
        float4 f = *reinterpret_cast<const float4*>(&in[(size_t)(k0 + r) * N + n0 + c]);
        tile[r][c] = (half_t)f.x; tile[r][c + 1] = (half_t)f.y;
        tile[r][c + 2] = (half_t)f.z; tile[r][c + 3] = (half_t)f.w;
    }
    __syncthreads();
    {
        const int rn = tid >> 3, ck = (tid & 7) * 4;
        f16x4 u;
        u[0] = tile[ck][rn]; u[1] = tile[ck + 1][rn];
        u[2] = tile[ck + 2][rn]; u[3] = tile[ck + 3][rn];
        *reinterpret_cast<f16x4*>(&out[(size_t)(n0 + rn) * NC + k0 + ck]) = u;
    }
}

// ---------------- GEMM0: qkv = xh * Wat^T + ba. 128x192 tile -> grid 64x12 = 768 blocks ----------------
// R8 WIN: grid 768 = exactly 3/CU, balanced. V n-tiles (n0 >= 1536) write Vt[bh][d][t]
// directly via wave-private 8KB LDS transpose (two 48-col passes).
__global__ __launch_bounds__(256, 3) void k_gemm0(const half_t* __restrict__ A, const half_t* __restrict__ Bt,
                                                  const float* __restrict__ bias, half_t* __restrict__ out,
                                                  half_t* __restrict__ Vt) {
    __shared__ half_t As[2][128 * 32];
    __shared__ half_t Bs[2][192 * 32];
    const int tid = threadIdx.x;
    const int lane = tid & 63, w = tid >> 6;
    const int m0 = blockIdx.x * 128, n0 = blockIdx.y * 192;
    const int wm = (w >> 1) * 64, wn = (w & 1) * 96;
    const int lr = lane & 15, lk = (lane >> 4) * 8;

    f32x4 acc[4][6];
#pragma unroll
    for (int a = 0; a < 4; ++a)
#pragma unroll
        for (int bq = 0; bq < 6; ++bq) acc[a][bq] = (f32x4){0.f, 0.f, 0.f, 0.f};

    const int ldsbase = (tid & ~63) * 16;   // wave-uniform byte base for global_load_lds
    const half_t* Arow = A  + (size_t)(m0 + (tid >> 2)) * NC + (tid & 3) * 8;
    const half_t* Brow = Bt + (size_t)(n0 + (tid >> 2)) * NC + (tid & 3) * 8;

    auto stage = [&](int buf, int k0) {
        load_lds16(Arow + k0,                    (char*)&As[buf][0] + ldsbase);
        load_lds16(Arow + (size_t)64 * NC + k0,  (char*)&As[buf][0] + 4096 + ldsbase);
        load_lds16(Brow + k0,                    (char*)&Bs[buf][0] + ldsbase);
        load_lds16(Brow + (size_t)64 * NC + k0,  (char*)&Bs[buf][0] + 4096 + ldsbase);
        load_lds16(Brow + (size_t)128 * NC + k0, (char*)&Bs[buf][0] + 8192 + ldsbase);
    };

    stage(0, 0);
    __syncthreads();
    int cur = 0;

    for (int ks = 0; ks < 24; ++ks) {
        if (ks < 23) stage(cur ^ 1, (ks + 1) * 32);
        f16x8 af[4];
#pragma unroll
        for (int mi = 0; mi < 4; ++mi)
            af[mi] = *reinterpret_cast<const f16x8*>(&As[cur][(wm + mi * 16 + lr) * 32 + lk]);
#pragma unroll
        for (int ni = 0; ni < 6; ++ni) {
            f16x8 bf = *reinterpret_cast<const f16x8*>(&Bs[cur][(wn + ni * 16 + lr) * 32 + lk]);
#pragma unroll
            for (int mi = 0; mi < 4; ++mi)
                acc[mi][ni] = MFMA16(af[mi], bf, acc[mi][ni]);
        }
        __syncthreads();   // drains stage vmcnt (overlapped by compute) + fences buf reads
        cur ^= 1;
    }

    const int rg = (lane >> 4) * 4;   // C/D layout: row=(lane>>4)*4+i, col=lane&15

    if (n0 >= 2 * NC) {
        // ---- V epilogue: two 48-col passes, wave-private 8KB LDS scratch ----
        half_t* q = (w < 2) ? (half_t*)((char*)&As[0][0] + w * 8192)
                            : (half_t*)((char*)&Bs[0][0] + (w - 2) * 8192);
        const int M0 = m0 + wm;
        const int bb = M0 >> 12;
        const int trow = M0 & (NT - 1);
#pragma unroll
        for (int p = 0; p < 2; ++p) {
#pragma unroll
            for (int n3 = 0; n3 < 3; ++n3) {
                const int ni = p * 3 + n3;
                const int c = n3 * 16 + lr;                  // local col 0..47
                const float bv = bias[n0 + wn + p * 48 + c];
                const int xsw = (c & 7) << 3;
#pragma unroll
                for (int mi = 0; mi < 4; ++mi) {
                    const int t0 = mi * 16 + rg;             // 4-aligned, XOR bits 3-5 only
                    union { f16x4 v; fp16x2 hh[2]; } o;
                    o.hh[0] = __builtin_amdgcn_cvt_pkrtz(acc[mi][ni][0] + bv, acc[mi][ni][1] + bv);
                    o.hh[1] = __builtin_amdgcn_cvt_pkrtz(acc[mi][ni][2] + bv, acc[mi][ni][3] + bv);
                    *reinterpret_cast<f16x4*>(&q[c * 64 + (t0 ^ xsw)]) = o.v;
                }
            }
            // wave-local read-back (same-wave DS ops are in-order; no block barrier)
#pragma unroll
            for (int j = 0; j < 6; ++j) {
                const int cl = j * 8 + (lane >> 3);          // local col 0..47
                const int tt = (lane & 7) * 8;               // 8-aligned
                f16x8 val = *reinterpret_cast<const f16x8*>(&q[cl * 64 + (tt ^ ((cl & 7) << 3))]);
                const int dcol = n0 - 2 * NC + wn + p * 48 + cl;   // 0..767
                const int bh = bb * NH + (dcol >> 6);
                *reinterpret_cast<f16x8*>(&Vt[((size_t)bh * ND + (dcol & 63)) * NT + trow + tt]) = val;
            }
        }
        return;
    }

    // ---- QK epilogue: f16 to qkvh (row stride NQKV) ----
#pragma unroll
    for (int ni = 0; ni < 6; ++ni) {
        const int gn = n0 + wn + ni * 16 + lr;
        const float bv = bias[gn];
#pragma unroll
        for (int mi = 0; mi < 4; ++mi)
#pragma unroll
            for (int i = 0; i < 4; ++i) {
                const size_t gm = (size_t)(m0 + wm + mi * 16 + rg + i);
                out[gm * NQKV + gn] = (half_t)(acc[mi][ni][i] + bv);
            }
    }
}

// ---------------- GEMM1: out = yh * Wpt^T + bp. 128x96 tile -> grid 64x8 = 512 blocks = 2/CU ----------------
__global__ __launch_bounds__(256) void k_gemm1(const half_t* __restrict__ A, const half_t* __restrict__ Bt,
                                               const float* __restrict__ bias, float* __restrict__ out) {
    __shared__ half_t As[2][128 * 32];
    __shared__ half_t Bs[2][128 * 32];   // rows 96..127 = staging overrun pad
    const int tid = threadIdx.x;
    const int lane = tid & 63, w = tid >> 6;
    const int m0 = blockIdx.x * 128, n0 = blockIdx.y * 96;
    const int wm = (w >> 1) * 64, wn = (w & 1) * 48;
    const int lr = lane & 15, lk = (lane >> 4) * 8;

    f32x4 acc[4][3];
#pragma unroll
    for (int a = 0; a < 4; ++a)
#pragma unroll
        for (int bq = 0; bq < 3; ++bq) acc[a][bq] = (f32x4){0.f, 0.f, 0.f, 0.f};

    const int ldsbase = (tid & ~63) * 16;   // wave-uniform byte base for global_load_lds
    const half_t* Arow = A  + (size_t)(m0 + (tid >> 2)) * NC + (tid & 3) * 8;
    const half_t* Brow = Bt + (size_t)(n0 + (tid >> 2)) * NC + (tid & 3) * 8;

    auto stage = [&](int buf, int k0) {
        load_lds16(Arow + k0,                   (char*)&As[buf][0] + ldsbase);
        load_lds16(Arow + (size_t)64 * NC + k0, (char*)&As[buf][0] + 4096 + ldsbase);
        load_lds16(Brow + k0,                   (char*)&Bs[buf][0] + ldsbase);
        load_lds16(Brow + (size_t)64 * NC + k0, (char*)&Bs[buf][0] + 4096 + ldsbase);
    };

    stage(0, 0);
    __syncthreads();
    int cur = 0;

    for (int ks = 0; ks < 24; ++ks) {
        if (ks < 23) stage(cur ^ 1, (ks + 1) * 32);
        f16x8 af[4], bf[3];
#pragma unroll
        for (int mi = 0; mi < 4; ++mi)
            af[mi] = *reinterpret_cast<const f16x8*>(&As[cur][(wm + mi * 16 + lr) * 32 + lk]);
#pragma unroll
        for (int ni = 0; ni < 3; ++ni)
            bf[ni] = *reinterpret_cast<const f16x8*>(&Bs[cur][(wn + ni * 16 + lr) * 32 + lk]);
#pragma unroll
        for (int mi = 0; mi < 4; ++mi)
#pragma unroll
            for (int ni = 0; ni < 3; ++ni)
                acc[mi][ni] = MFMA16(af[mi], bf[ni], acc[mi][ni]);
        __syncthreads();
        cur ^= 1;
    }

    const int rg = (lane >> 4) * 4;   // C/D layout: row=(lane>>4)*4+i, col=lane&15
#pragma unroll
    for (int ni = 0; ni < 3; ++ni) {
        const int gn = n0 + wn + ni * 16 + lr;
        const float bv = bias[gn];
#pragma unroll
        for (int mi = 0; mi < 4; ++mi)
#pragma unroll
            for (int i = 0; i < 4; ++i) {
                const size_t gm = (size_t)(m0 + wm + mi * 16 + rg + i);
                out[gm * NC + gn] = acc[mi][ni][i] + bv;
            }
    }
}

// ---------------- Flash attention v11: v9 structure on mfma_32x32x16 ----------------
// R10: v9 was at ~90% combined VALU+MFMA issue (51%+38.6%). exp2 is irreducible; MFMA
// pipe time is not: 32x32x16 does 4x the FLOP of 16x16x32 in 8cy vs 5cy -> 20% less
// pipe time, 50% fewer MFMA issue slots, identical LDS traffic and exp2 count.
// Zero-shuffle port: swapped QKT mfma32(K,Q) -> S: q=lane&31, key=(reg&3)+8(reg>>2)+4lh
// (lh=lane>>5). PV B-operand (q=lane&31, slot=(lh)*8+j) with key-permutation
// kappa(lh,j) = (j&3)+8*(j>>2)+4*lh (+16*ks2, +32*kw) equals the lane-local packed exp
// values exactly (zero cross-lane movement); matching V A-fragment = two b64 reads at
// chunks (kw*4+ks2*2+j)^psw -- same read family as v9. Per wave-iter: 8 QKT + 8 PV
// MFMA (was 16+16), 4 b128 + 8 b64 LDS reads (same), 32 exp2 (same).
struct __align__(16) AttnSmem {
    union {
        struct { half_t K[2][64 * 64]; half_t V[2][64 * 64]; } m;   // 32 KB main
        struct { float y[2][64][64]; float l[2][64][4]; } r;        // 34 KB epilogue
    };
};

__global__ __launch_bounds__(256, 3) void k_attn(const half_t* __restrict__ qkv, const half_t* __restrict__ Vt,
                                                 half_t* __restrict__ Y) {
    __shared__ AttnSmem sm;
    const int tid = threadIdx.x, lane = tid & 63, w = tid >> 6;
    const int qw = w & 1, kw = w >> 1;
    const int ln = lane & 31, lh = lane >> 5;
    const int qt = blockIdx.x, bh = blockIdx.y;
    const int b = bh / NH, h = bh - b * NH;
    const half_t* Qp = qkv + (size_t)b * NT * NQKV + h * ND;        // q cols
    const half_t* Kp = Qp + NC;                                     // k cols
    const half_t* Vbase = Vt + (size_t)bh * ND * NT;                // V^T [d][t]
    const int q0 = qt * 128 + qw * 64;

    // staging geometry: 256 threads x 16B = 4KB per instr = 32 rows of 128B; 2 instrs per 8KB tile
    const int sr = tid >> 3;                                   // row 0..31 (instr0), +32 (instr1)
    const int colh = (((tid & 7) << 3)) ^ ((sr & 7) << 3);     // swizzled source col (halfs)
    const int wub = (tid & ~63) * 16;                          // wave-uniform LDS byte base

    // Q fragments (B-operand: col=q=ln, k-slot=lh*8+j over K=16 d): aq[qt2][dk],
    // d = dk*16 + lh*8 + j. Pre-scaled by 1/sqrt(D)*log2(e).
    f16x8 aq[2][4];
    const half_t cch = (half_t)(0.125f * 1.4426950408889634f);
#pragma unroll
    for (int q2 = 0; q2 < 2; ++q2)
#pragma unroll
        for (int dk = 0; dk < 4; ++dk) {
            aq[q2][dk] = *reinterpret_cast<const f16x8*>(&Qp[(size_t)(q0 + q2 * 32 + ln) * NQKV + dk * 16 + lh * 8]);
#pragma unroll
            for (int j = 0; j < 8; ++j) aq[q2][dk][j] = aq[q2][dk][j] * cch;
        }

    // K-read (A-operand): row = key = kw*32+ln; d-chunk dk*2+lh, swizzled by row&7 = ln&7
    const int krow = kw * 32 + ln;
    const int ksw = ln & 7;
    int kcol[4];
#pragma unroll
    for (int dk = 0; dk < 4; ++dk) kcol[dk] = (((dk << 1) | lh) ^ ksw) << 3;   // half offset

    // V-read (A-operand): row = d = dt*32+ln; per ks2, two b64 at chunks (kw*4+ks2*2+j)^psw
    const int psw = ln & 7;
    const int goff = lh * 4;
    const int vcol[2][2] = { { ((kw * 4 + 0) ^ psw) * 8 + goff, ((kw * 4 + 1) ^ psw) * 8 + goff },
                             { ((kw * 4 + 2) ^ psw) * 8 + goff, ((kw * 4 + 3) ^ psw) * 8 + goff } };

    const f32x16 z16 = {0.f,0.f,0.f,0.f, 0.f,0.f,0.f,0.f, 0.f,0.f,0.f,0.f, 0.f,0.f,0.f,0.f};
    f32x16 y_[2][2];
#pragma unroll
    for (int q2 = 0; q2 < 2; ++q2) { y_[q2][0] = z16; y_[q2][1] = z16; }
    float l_[2] = {0.f, 0.f};

    auto stagebuf = [&](int buf, const half_t* Ks, const half_t* Vs) {
        char* kdst = (char*)&sm.m.K[buf][0] + wub;
        char* vdst = (char*)&sm.m.V[buf][0] + wub;
        load_lds16(Ks, kdst);
        load_lds16(Ks + (size_t)32 * NQKV, kdst + 4096);
        load_lds16(Vs, vdst);
        load_lds16(Vs + (size_t)32 * NT, vdst + 4096);
    };

    const half_t* ksrc = Kp + (size_t)sr * NQKV + colh;
    const half_t* vsrc = Vbase + (size_t)sr * NT + colh;
    stagebuf(0, ksrc, vsrc);
    ksrc += (size_t)64 * NQKV;
    vsrc += 64;
    __syncthreads();
    int cur = 0;

    for (int t = 0; t < NT / 64; ++t) {
        if (t < NT / 64 - 1) {
            stagebuf(cur ^ 1, ksrc, vsrc);
            ksrc += (size_t)64 * NQKV;
            vsrc += 64;
        }

        // ---- QK^T (swapped, 32x32x16): s_[q2] covers 32 keys x 32 q ----
        f32x16 s_[2];
        s_[0] = z16; s_[1] = z16;
        const half_t* Kc = &sm.m.K[cur][0];
        __builtin_amdgcn_s_setprio(1);
#pragma unroll
        for (int dk = 0; dk < 4; ++dk) {
            f16x8 ak = *reinterpret_cast<const f16x8*>(&Kc[krow * 64 + kcol[dk]]);
            s_[0] = MFMA32(ak, aq[0][dk], s_[0]);
            s_[1] = MFMA32(ak, aq[1][dk], s_[1]);
        }
        __builtin_amdgcn_s_setprio(0);

        // ---- no-max softmax + lane-local pack: pb[q2][ks2] = packed exp of s regs ks2*8.. ----
        f16x8 pb[2][2];
#pragma unroll
        for (int q2 = 0; q2 < 2; ++q2) {
            float ps = 0.f;
#pragma unroll
            for (int ks2 = 0; ks2 < 2; ++ks2) {
                union { f16x8 v; fp16x2 hh[4]; } u;
#pragma unroll
                for (int jp = 0; jp < 4; ++jp) {
                    const float pa = __builtin_amdgcn_exp2f(s_[q2][ks2 * 8 + jp * 2]);
                    const float pc = __builtin_amdgcn_exp2f(s_[q2][ks2 * 8 + jp * 2 + 1]);
                    u.hh[jp] = __builtin_amdgcn_cvt_pkrtz(pa, pc);
                    ps += pa + pc;
                }
                pb[q2][ks2] = u.v;
            }
            l_[q2] += ps;
        }

        // ---- PV (32x32x16): A = V rows (d=dt*32+ln), k-permuted; B = pb (register) ----
        const half_t* Vc = &sm.m.V[cur][0];
        __builtin_amdgcn_s_setprio(1);
#pragma unroll
        for (int dt = 0; dt < 2; ++dt) {
            const half_t* vrow = &Vc[(dt * 32 + ln) * 64];
#pragma unroll
            for (int ks2 = 0; ks2 < 2; ++ks2) {
                union { f16x8 v; f16x4 q[2]; } va;
                va.q[0] = *reinterpret_cast<const f16x4*>(vrow + vcol[ks2][0]);
                va.q[1] = *reinterpret_cast<const f16x4*>(vrow + vcol[ks2][1]);
                y_[0][dt] = MFMA32(va.v, pb[0][ks2], y_[0][dt]);
                y_[1][dt] = MFMA32(va.v, pb[1][ks2], y_[1][dt]);
            }
        }
        __builtin_amdgcn_s_setprio(0);

        __syncthreads();   // drains stage vmcnt + all waves done reading buf[cur]
        cur ^= 1;
    }

    // lane pair (ln, ln+32) holds complementary key sets for the same q
    l_[0] += __shfl_xor(l_[0], 32);
    l_[1] += __shfl_xor(l_[1], 32);

    // ---- cross-wave (key-half) reduction: kw=1 publishes y/l, kw=0 combines+stores ----
    if (kw == 1) {
#pragma unroll
        for (int q2 = 0; q2 < 2; ++q2)
#pragma unroll
            for (int dt = 0; dt < 2; ++dt)
#pragma unroll
                for (int r = 0; r < 4; ++r) {
                    const int c = q2 * 8 + dt * 4 + r;
                    const int jb = (c * 4) ^ ((lane & 7) << 2);   // bank swizzle
                    f32x4 tv;
                    tv[0] = y_[q2][dt][4 * r];     tv[1] = y_[q2][dt][4 * r + 1];
                    tv[2] = y_[q2][dt][4 * r + 2]; tv[3] = y_[q2][dt][4 * r + 3];
                    *reinterpret_cast<f32x4*>(&sm.r.y[qw][lane][jb]) = tv;
                }
        sm.r.l[qw][lane][0] = l_[0];
        sm.r.l[qw][lane][1] = l_[1];
    }
    __syncthreads();
    if (kw == 0) {
#pragma unroll
        for (int q2 = 0; q2 < 2; ++q2) {
            const float l = l_[q2] + sm.r.l[qw][lane][q2];
            const float rl = 1.f / l;
            half_t* Yp = Y + (size_t)(b * NT + q0 + q2 * 32 + ln) * NC + h * ND;
#pragma unroll
            for (int dt = 0; dt < 2; ++dt)
#pragma unroll
                for (int r = 0; r < 4; ++r) {
                    const int c = q2 * 8 + dt * 4 + r;
                    const int jb = (c * 4) ^ ((lane & 7) << 2);
                    const f32x4 yp = *reinterpret_cast<const f32x4*>(&sm.r.y[qw][lane][jb]);
                    union { f16x4 v; fp16x2 hh[2]; } o;
                    o.hh[0] = __builtin_amdgcn_cvt_pkrtz((y_[q2][dt][4 * r] + yp[0]) * rl,
                                                         (y_[q2][dt][4 * r + 1] + yp[1]) * rl);
                    o.hh[1] = __builtin_amdgcn_cvt_pkrtz((y_[q2][dt][4 * r + 2] + yp[2]) * rl,
                                                         (y_[q2][dt][4 * r + 3] + yp[3]) * rl);
                    // d = dt*32 + 8*r + 4*lh + (0..3)
                    *reinterpret_cast<f16x4*>(Yp + dt * 32 + 8 * r + 4 * lh) = o.v;
                }
        }
    }
}

extern "C" void kernel_launch(void* const* d_in, const int* in_sizes, int n_in,
                              void* d_out, int out_size, void* d_ws, size_t ws_size,
                              hipStream_t stream) {
    const float* x  = (const float*)d_in[0];
    const float* Wa = (const float*)d_in[1];
    const float* ba = (const float*)d_in[2];
    const float* Wp = (const float*)d_in[3];
    const float* bp = (const float*)d_in[4];
    float* out = (float*)d_out;

    char* ws = (char*)d_ws;
    half_t* xh   = (half_t*)ws; ws += (size_t)NBT * NC * 2;
    half_t* Wat  = (half_t*)ws; ws += (size_t)NQKV * NC * 2;
    half_t* Wpt  = (half_t*)ws; ws += (size_t)NC * NC * 2;
    half_t* qkvh = (half_t*)ws; ws += (size_t)NBT * NQKV * 2;
    half_t* vt   = (half_t*)ws; ws += (size_t)NB * NH * ND * NT * 2;
    half_t* yh   = (half_t*)ws; ws += (size_t)NBT * NC * 2;

    k_prep<<<PREP_BLKS, 256, 0, stream>>>(x, xh, Wa, Wat, Wp, Wpt);
    k_gemm0<<<dim3(NBT / 128, NQKV / 192), 256, 0, stream>>>(xh, Wat, ba, qkvh, vt);
    k_attn<<<dim3(NT / 128, NB * NH), 256, 0, stream>>>(qkvh, vt, yh);
    k_gemm1<<<dim3(NBT / 128, NC / 96), 256, 0, stream>>>(yh, Wpt, bp, out);
}

// Round 12
// 184.208 us; speedup vs baseline: 1.0434x; 1.0434x over previous
//
#include <hip/hip_runtime.h>
#include <stdint.h>

#define NB 2
#define NT 4096
#define NC 768
#define NH 12
#define ND 64
#define NBT (NB*NT)      // 8192
#define NQKV (3*NC)      // 2304

typedef _Float16 half_t;
typedef __attribute__((ext_vector_type(8))) _Float16 f16x8;
typedef __attribute__((ext_vector_type(4))) _Float16 f16x4;
typedef __attribute__((ext_vector_type(2))) __fp16 fp16x2;   // native type of cvt_pkrtz
typedef __attribute__((ext_vector_type(4))) float f32x4;

#define MFMA16(a,b,c) __builtin_amdgcn_mfma_f32_16x16x32_f16((a),(b),(c),0,0,0)

__device__ __forceinline__ void load_lds16(const void* g, void* l) {
    auto gp = reinterpret_cast<__attribute__((address_space(1))) char*>(reinterpret_cast<uintptr_t>(g));
    auto lp = reinterpret_cast<__attribute__((address_space(3))) char*>(reinterpret_cast<uintptr_t>(l));
    __builtin_amdgcn_global_load_lds(gp, lp, 16, 0, 0);
}

// ---------------- prep: fused {pack x fp32->f16} + {tiled transpose Wa} + {tiled transpose Wp} ----------------
#define PACK_BLKS ((NBT * NC / 4) / 256)          // 6144
#define WA_TILES ((NC / 32) * (NQKV / 32))        // 24*72 = 1728
#define WP_TILES ((NC / 32) * (NC / 32))          // 24*24 = 576
#define PREP_BLKS (PACK_BLKS + WA_TILES + WP_TILES)

__global__ __launch_bounds__(256) void k_prep(const float* __restrict__ x, half_t* __restrict__ xh,
                                              const float* __restrict__ Wa, half_t* __restrict__ Wat,
                                              const float* __restrict__ Wp, half_t* __restrict__ Wpt) {
    const int bid = blockIdx.x, tid = threadIdx.x;
    if (bid < PACK_BLKS) {
        const int i = bid * 256 + tid;
        float4 f = reinterpret_cast<const float4*>(x)[i];
        f16x4 h;
        h[0] = (half_t)f.x; h[1] = (half_t)f.y; h[2] = (half_t)f.z; h[3] = (half_t)f.w;
        reinterpret_cast<f16x4*>(xh)[i] = h;
        return;
    }
    __shared__ half_t tile[32][36];
    const float* in; half_t* out; int N, kt, nt;
    if (bid < PACK_BLKS + WA_TILES) {
        const int t = bid - PACK_BLKS;
        in = Wa; out = Wat; N = NQKV;
        kt = t / (NQKV / 32); nt = t - kt * (NQKV / 32);
    } else {
        const int t = bid - PACK_BLKS - WA_TILES;
        in = Wp; out = Wpt; N = NC;
        kt = t / (NC / 32); nt = t - kt * (NC / 32);
    }
    const int k0 = kt * 32, n0 = nt * 32;
    {
        const int r = tid >> 3, c = (tid & 7) * 4;
        float4 f = *reinterpret_cast<const float4*>(&in[(size_t)(k0 + r) * N + n0 + c]);
        tile[r][c] = (half_t)f.x; tile[r][c + 1] = (half_t)f.y;
        tile[r][c + 2] = (half_t)f.z; tile[r][c + 3] = (half_t)f.w;
    }
    __syncthreads();
    {
        const int rn = tid >> 3, ck = (tid & 7) * 4;
        f16x4 u;
        u[0] = tile[ck][rn]; u[1] = tile[ck + 1][rn];
        u[2] = tile[ck + 2][rn]; u[3] = tile[ck + 3][rn];
        *reinterpret_cast<f16x4*>(&out[(size_t)(n0 + rn) * NC + k0 + ck]) = u;
    }
}

// ---------------- GEMM0: qkv = xh * Wat^T + ba. 128x192 tile -> grid 64x12 = 768 blocks ----------------
// R8 WIN: grid 768 = exactly 3/CU, balanced (was 1152 -> 1.5 dispatch rounds).
// V n-tiles (n0 >= 1536 = 8*192) skip qkvh and write Vt[bh][d][t] via wave-private 8KB
// LDS transpose in two 48-col passes (wave-local; same XOR swizzle family as R7).
__global__ __launch_bounds__(256, 3) void k_gemm0(const half_t* __restrict__ A, const half_t* __restrict__ Bt,
                                                  const float* __restrict__ bias, half_t* __restrict__ out,
                                                  half_t* __restrict__ Vt) {
    __shared__ half_t As[2][128 * 32];
    __shared__ half_t Bs[2][192 * 32];
    const int tid = threadIdx.x;
    const int lane = tid & 63, w = tid >> 6;
    const int m0 = blockIdx.x * 128, n0 = blockIdx.y * 192;
    const int wm = (w >> 1) * 64, wn = (w & 1) * 96;
    const int lr = lane & 15, lk = (lane >> 4) * 8;

    f32x4 acc[4][6];
#pragma unroll
    for (int a = 0; a < 4; ++a)
#pragma unroll
        for (int bq = 0; bq < 6; ++bq) acc[a][bq] = (f32x4){0.f, 0.f, 0.f, 0.f};

    const int ldsbase = (tid & ~63) * 16;   // wave-uniform byte base for global_load_lds
    const half_t* Arow = A  + (size_t)(m0 + (tid >> 2)) * NC + (tid & 3) * 8;
    const half_t* Brow = Bt + (size_t)(n0 + (tid >> 2)) * NC + (tid & 3) * 8;

    auto stage = [&](int buf, int k0) {
        load_lds16(Arow + k0,                    (char*)&As[buf][0] + ldsbase);
        load_lds16(Arow + (size_t)64 * NC + k0,  (char*)&As[buf][0] + 4096 + ldsbase);
        load_lds16(Brow + k0,                    (char*)&Bs[buf][0] + ldsbase);
        load_lds16(Brow + (size_t)64 * NC + k0,  (char*)&Bs[buf][0] + 4096 + ldsbase);
        load_lds16(Brow + (size_t)128 * NC + k0, (char*)&Bs[buf][0] + 8192 + ldsbase);
    };

    stage(0, 0);
    __syncthreads();
    int cur = 0;

    for (int ks = 0; ks < 24; ++ks) {
        if (ks < 23) stage(cur ^ 1, (ks + 1) * 32);
        f16x8 af[4];
#pragma unroll
        for (int mi = 0; mi < 4; ++mi)
            af[mi] = *reinterpret_cast<const f16x8*>(&As[cur][(wm + mi * 16 + lr) * 32 + lk]);
#pragma unroll
        for (int ni = 0; ni < 6; ++ni) {
            f16x8 bf = *reinterpret_cast<const f16x8*>(&Bs[cur][(wn + ni * 16 + lr) * 32 + lk]);
#pragma unroll
            for (int mi = 0; mi < 4; ++mi)
                acc[mi][ni] = MFMA16(af[mi], bf, acc[mi][ni]);
        }
        __syncthreads();   // drains stage vmcnt (overlapped by compute) + fences buf reads
        cur ^= 1;
    }

    const int rg = (lane >> 4) * 4;   // C/D layout: row=(lane>>4)*4+i, col=lane&15

    if (n0 >= 2 * NC) {
        // ---- V epilogue: two 48-col passes, wave-private 8KB LDS scratch ----
        half_t* q = (w < 2) ? (half_t*)((char*)&As[0][0] + w * 8192)
                            : (half_t*)((char*)&Bs[0][0] + (w - 2) * 8192);
        const int M0 = m0 + wm;
        const int bb = M0 >> 12;
        const int trow = M0 & (NT - 1);
#pragma unroll
        for (int p = 0; p < 2; ++p) {
#pragma unroll
            for (int n3 = 0; n3 < 3; ++n3) {
                const int ni = p * 3 + n3;
                const int c = n3 * 16 + lr;                  // local col 0..47
                const float bv = bias[n0 + wn + p * 48 + c];
                const int xsw = (c & 7) << 3;
#pragma unroll
                for (int mi = 0; mi < 4; ++mi) {
                    const int t0 = mi * 16 + rg;             // 4-aligned, XOR bits 3-5 only
                    union { f16x4 v; fp16x2 hh[2]; } o;
                    o.hh[0] = __builtin_amdgcn_cvt_pkrtz(acc[mi][ni][0] + bv, acc[mi][ni][1] + bv);
                    o.hh[1] = __builtin_amdgcn_cvt_pkrtz(acc[mi][ni][2] + bv, acc[mi][ni][3] + bv);
                    *reinterpret_cast<f16x4*>(&q[c * 64 + (t0 ^ xsw)]) = o.v;
                }
            }
            // wave-local read-back (same-wave DS ops are in-order; no block barrier)
#pragma unroll
            for (int j = 0; j < 6; ++j) {
                const int cl = j * 8 + (lane >> 3);          // local col 0..47
                const int tt = (lane & 7) * 8;               // 8-aligned
                f16x8 val = *reinterpret_cast<const f16x8*>(&q[cl * 64 + (tt ^ ((cl & 7) << 3))]);
                const int dcol = n0 - 2 * NC + wn + p * 48 + cl;   // 0..767
                const int bh = bb * NH + (dcol >> 6);
                *reinterpret_cast<f16x8*>(&Vt[((size_t)bh * ND + (dcol & 63)) * NT + trow + tt]) = val;
            }
        }
        return;
    }

    // ---- QK epilogue: f16 to qkvh (row stride NQKV) ----
#pragma unroll
    for (int ni = 0; ni < 6; ++ni) {
        const int gn = n0 + wn + ni * 16 + lr;
        const float bv = bias[gn];
#pragma unroll
        for (int mi = 0; mi < 4; ++mi)
#pragma unroll
            for (int i = 0; i < 4; ++i) {
                const size_t gm = (size_t)(m0 + wm + mi * 16 + rg + i);
                out[gm * NQKV + gn] = (half_t)(acc[mi][ni][i] + bv);
            }
    }
}

// ---------------- GEMM1: out = yh * Wpt^T + bp. 128x96 tile -> grid 64x8 = 512 blocks = 2/CU ----------------
// R9: 128x96 gives 512 blocks = exactly 2/CU balanced (vs 384 blocks = half the CUs 2x
// loaded). Bs rows 96..127 = staging overrun pad (lands in adjacent workspace, never read).
__global__ __launch_bounds__(256) void k_gemm1(const half_t* __restrict__ A, const half_t* __restrict__ Bt,
                                               const float* __restrict__ bias, float* __restrict__ out) {
    __shared__ half_t As[2][128 * 32];
    __shared__ half_t Bs[2][128 * 32];   // rows 96..127 = staging overrun pad
    const int tid = threadIdx.x;
    const int lane = tid & 63, w = tid >> 6;
    const int m0 = blockIdx.x * 128, n0 = blockIdx.y * 96;
    const int wm = (w >> 1) * 64, wn = (w & 1) * 48;
    const int lr = lane & 15, lk = (lane >> 4) * 8;

    f32x4 acc[4][3];
#pragma unroll
    for (int a = 0; a < 4; ++a)
#pragma unroll
        for (int bq = 0; bq < 3; ++bq) acc[a][bq] = (f32x4){0.f, 0.f, 0.f, 0.f};

    const int ldsbase = (tid & ~63) * 16;   // wave-uniform byte base for global_load_lds
    const half_t* Arow = A  + (size_t)(m0 + (tid >> 2)) * NC + (tid & 3) * 8;
    const half_t* Brow = Bt + (size_t)(n0 + (tid >> 2)) * NC + (tid & 3) * 8;

    auto stage = [&](int buf, int k0) {
        load_lds16(Arow + k0,                   (char*)&As[buf][0] + ldsbase);
        load_lds16(Arow + (size_t)64 * NC + k0, (char*)&As[buf][0] + 4096 + ldsbase);
        load_lds16(Brow + k0,                   (char*)&Bs[buf][0] + ldsbase);
        load_lds16(Brow + (size_t)64 * NC + k0, (char*)&Bs[buf][0] + 4096 + ldsbase);
    };

    stage(0, 0);
    __syncthreads();
    int cur = 0;

    for (int ks = 0; ks < 24; ++ks) {
        if (ks < 23) stage(cur ^ 1, (ks + 1) * 32);
        f16x8 af[4], bf[3];
#pragma unroll
        for (int mi = 0; mi < 4; ++mi)
            af[mi] = *reinterpret_cast<const f16x8*>(&As[cur][(wm + mi * 16 + lr) * 32 + lk]);
#pragma unroll
        for (int ni = 0; ni < 3; ++ni)
            bf[ni] = *reinterpret_cast<const f16x8*>(&Bs[cur][(wn + ni * 16 + lr) * 32 + lk]);
#pragma unroll
        for (int mi = 0; mi < 4; ++mi)
#pragma unroll
            for (int ni = 0; ni < 3; ++ni)
                acc[mi][ni] = MFMA16(af[mi], bf[ni], acc[mi][ni]);
        __syncthreads();
        cur ^= 1;
    }

    const int rg = (lane >> 4) * 4;   // C/D layout: row=(lane>>4)*4+i, col=lane&15
#pragma unroll
    for (int ni = 0; ni < 3; ++ni) {
        const int gn = n0 + wn + ni * 16 + lr;
        const float bv = bias[gn];
#pragma unroll
        for (int mi = 0; mi < 4; ++mi)
#pragma unroll
            for (int i = 0; i < 4; ++i) {
                const size_t gm = (size_t)(m0 + wm + mi * 16 + rg + i);
                out[gm * NC + gn] = acc[mi][ni][i] + bv;
            }
    }
}

// ---------------- Flash attention v9: q=64/wave AND 12 waves/CU (qw x kw wave grid) ----------------
// FROZEN. Full ledger: R0 8w-split regressed (per-wave work too small per barrier);
// R1 counted-vmcnt neutral; R2 score-lookahead spilled (VGPR cap); R3 q=64 @ 6 waves/CU
// conflicts halved but latency-exposed; R4 = q=64 + 12 waves/CU: WIN 133->119us;
// R5 per-qf fusion regressed (broke phase-level ILP); R10 32x32-MFMA port regressed
// (4-way K-read conflicts +49%, dependent 8cy-MFMA chains stall: 119->126). 119us is
// this structure's measured floor: ~90% combined VALU+MFMA issue, exp2 irreducible.
struct __align__(16) AttnSmem {
    union {
        struct { half_t K[2][64 * 64]; half_t V[2][64 * 64]; } m;   // 32 KB main
        struct { float y[2][64][64]; float l[2][64][4]; } r;        // 34 KB epilogue
    };
};

__global__ __launch_bounds__(256, 3) void k_attn(const half_t* __restrict__ qkv, const half_t* __restrict__ Vt,
                                                 half_t* __restrict__ Y) {
    __shared__ AttnSmem sm;
    const int tid = threadIdx.x, lane = tid & 63, w = tid >> 6;
    const int qw = w & 1, kw = w >> 1;
    const int lr = lane & 15, g = lane >> 4;
    const int qt = blockIdx.x, bh = blockIdx.y;
    const int b = bh / NH, h = bh - b * NH;
    const half_t* Qp = qkv + (size_t)b * NT * NQKV + h * ND;        // q cols
    const half_t* Kp = Qp + NC;                                     // k cols
    const half_t* Vbase = Vt + (size_t)bh * ND * NT;                // V^T [d][t]
    const int q0 = qt * 128 + qw * 64;

    // staging geometry: 256 threads x 16B = 4KB per instr = 32 rows of 128B; 2 instrs per 8KB tile
    const int sr = tid >> 3;                                   // row 0..31 (instr0), +32 (instr1)
    const int colh = (((tid & 7) << 3)) ^ ((sr & 7) << 3);     // swizzled source col (halfs)
    const int wub = (tid & ~63) * 16;                          // wave-uniform LDS byte base

    // Q fragments (B-operand: col=lr=q), 4 q-frags x 2 d-halves, pre-scaled by 1/sqrt(D)*log2(e)
    f16x8 aq[4][2];
    const half_t cch = (half_t)(0.125f * 1.4426950408889634f);
#pragma unroll
    for (int qf = 0; qf < 4; ++qf)
#pragma unroll
        for (int dh = 0; dh < 2; ++dh) {
            aq[qf][dh] = *reinterpret_cast<const f16x8*>(&Qp[(size_t)(q0 + qf * 16 + lr) * NQKV + dh * 32 + g * 8]);
#pragma unroll
            for (int j = 0; j < 8; ++j) aq[qf][dh][j] = aq[qf][dh][j] * cch;
        }

    // swizzled K-read columns (b128): row = st*16+lr, chunk ^= (lr&7)
    const int swk = (lr & 7) << 3;
    const int cA = (g * 8) ^ swk;          // d-chunk 0
    const int cB = (32 + g * 8) ^ swk;     // d-chunk 1
    // swizzled V-read columns (b64 pairs) for this wave's key-half (ks = kw)
    const int psw = lr & 7;
    const int goff = (g & 1) << 2;
    const int vcol[2] = { (((g >> 1) + 4 * kw + 0) ^ psw) * 8 + goff,
                          (((g >> 1) + 4 * kw + 2) ^ psw) * 8 + goff };

    f32x4 y[4][4];
#pragma unroll
    for (int qf = 0; qf < 4; ++qf)
#pragma unroll
        for (int df = 0; df < 4; ++df) y[qf][df] = (f32x4){0.f, 0.f, 0.f, 0.f};
    float l_[4] = {0.f, 0.f, 0.f, 0.f};

    auto stagebuf = [&](int buf, const half_t* Ks, const half_t* Vs) {
        char* kdst = (char*)&sm.m.K[buf][0] + wub;
        char* vdst = (char*)&sm.m.V[buf][0] + wub;
        load_lds16(Ks, kdst);
        load_lds16(Ks + (size_t)32 * NQKV, kdst + 4096);
        load_lds16(Vs, vdst);
        load_lds16(Vs + (size_t)32 * NT, vdst + 4096);
    };

    const half_t* ksrc = Kp + (size_t)sr * NQKV + colh;
    const half_t* vsrc = Vbase + (size_t)sr * NT + colh;
    stagebuf(0, ksrc, vsrc);
    ksrc += (size_t)64 * NQKV;
    vsrc += 64;
    __syncthreads();
    int cur = 0;
    const int stb = 2 * kw;

    for (int t = 0; t < NT / 64; ++t) {
        if (t < NT / 64 - 1) {
            stagebuf(cur ^ 1, ksrc, vsrc);
            ksrc += (size_t)64 * NQKV;
            vsrc += 64;
        }

        // ---- QK^T (swapped), this wave's 32-key half: s[qf][sl][i], st = stb+sl ----
        f32x4 s[4][2];
#pragma unroll
        for (int qf = 0; qf < 4; ++qf) { s[qf][0] = (f32x4){0.f,0.f,0.f,0.f}; s[qf][1] = (f32x4){0.f,0.f,0.f,0.f}; }
        const half_t* Kc = &sm.m.K[cur][0];
        __builtin_amdgcn_s_setprio(1);
#pragma unroll
        for (int sl = 0; sl < 2; ++sl) {
            const int row = (stb + sl) * 16 + lr;
            f16x8 bk0 = *reinterpret_cast<const f16x8*>(&Kc[row * 64 + cA]);
            s[0][sl] = MFMA16(bk0, aq[0][0], s[0][sl]);
            s[1][sl] = MFMA16(bk0, aq[1][0], s[1][sl]);
            s[2][sl] = MFMA16(bk0, aq[2][0], s[2][sl]);
            s[3][sl] = MFMA16(bk0, aq[3][0], s[3][sl]);
            f16x8 bk1 = *reinterpret_cast<const f16x8*>(&Kc[row * 64 + cB]);
            s[0][sl] = MFMA16(bk1, aq[0][1], s[0][sl]);
            s[1][sl] = MFMA16(bk1, aq[1][1], s[1][sl]);
            s[2][sl] = MFMA16(bk1, aq[2][1], s[2][sl]);
            s[3][sl] = MFMA16(bk1, aq[3][1], s[3][sl]);
        }
        __builtin_amdgcn_s_setprio(0);

        // ---- no-max softmax + lane-local pack: pb[qf] = packed p for this key-half ----
        f16x8 pb[4];
#pragma unroll
        for (int qf = 0; qf < 4; ++qf) {
            float ps = 0.f;
            union { f16x8 v; fp16x2 h[4]; } u;
#pragma unroll
            for (int hs = 0; hs < 2; ++hs) {   // hs: local st within this ks
                const float p0 = __builtin_amdgcn_exp2f(s[qf][hs][0]);
                const float p1 = __builtin_amdgcn_exp2f(s[qf][hs][1]);
                const float p2 = __builtin_amdgcn_exp2f(s[qf][hs][2]);
                const float p3 = __builtin_amdgcn_exp2f(s[qf][hs][3]);
                u.h[2 * hs]     = __builtin_amdgcn_cvt_pkrtz(p0, p1);
                u.h[2 * hs + 1] = __builtin_amdgcn_cvt_pkrtz(p2, p3);
                ps += (p0 + p1) + (p2 + p3);
            }
            pb[qf] = u.v;
            l_[qf] += ps;
        }

        // ---- PV (ks = kw): A = V^T rows, B = pb (register) ----
        const half_t* Vc = &sm.m.V[cur][0];
        __builtin_amdgcn_s_setprio(1);
#pragma unroll
        for (int df = 0; df < 4; ++df) {
            const half_t* vrow = &Vc[(df * 16 + lr) * 64];
            union { f16x8 v; f16x4 q[2]; } va;
            va.q[0] = *reinterpret_cast<const f16x4*>(vrow + vcol[0]);
            va.q[1] = *reinterpret_cast<const f16x4*>(vrow + vcol[1]);
            y[0][df] = MFMA16(va.v, pb[0], y[0][df]);
            y[1][df] = MFMA16(va.v, pb[1], y[1][df]);
            y[2][df] = MFMA16(va.v, pb[2], y[2][df]);
            y[3][df] = MFMA16(va.v, pb[3], y[3][df]);
        }
        __builtin_amdgcn_s_setprio(0);

        __syncthreads();   // drains stage vmcnt + all waves done reading buf[cur]
        cur ^= 1;
    }

    // ---- cross-wave (key-half) reduction: kw=1 publishes y/l, kw=0 combines+stores ----
    if (kw == 1) {
#pragma unroll
        for (int qf = 0; qf < 4; ++qf)
#pragma unroll
            for (int df = 0; df < 4; ++df) {
                const int jb = (qf * 16 + df * 4) ^ ((lane & 7) << 2);   // bank swizzle
                *reinterpret_cast<f32x4*>(&sm.r.y[qw][lane][jb]) = y[qf][df];
            }
#pragma unroll
        for (int qf = 0; qf < 4; ++qf) sm.r.l[qw][lane][qf] = l_[qf];
    }
    __syncthreads();
    if (kw == 0) {
#pragma unroll
        for (int qf = 0; qf < 4; ++qf) {
#pragma unroll
            for (int df = 0; df < 4; ++df) {
                const int jb = (qf * 16 + df * 4) ^ ((lane & 7) << 2);
                const f32x4 yp = *reinterpret_cast<const f32x4*>(&sm.r.y[qw][lane][jb]);
                y[qf][df] += yp;
            }
            float l = l_[qf] + sm.r.l[qw][lane][qf];
            l += __shfl_xor(l, 16);
            l += __shfl_xor(l, 32);
            const float rl = 1.f / l;
            half_t* Yp = Y + (size_t)(b * NT + q0 + qf * 16 + lr) * NC + h * ND + g * 4;
#pragma unroll
            for (int df = 0; df < 4; ++df) {
                union { f16x4 v; fp16x2 hh[2]; } o;
                o.hh[0] = __builtin_amdgcn_cvt_pkrtz(y[qf][df][0] * rl, y[qf][df][1] * rl);
                o.hh[1] = __builtin_amdgcn_cvt_pkrtz(y[qf][df][2] * rl, y[qf][df][3] * rl);
                *reinterpret_cast<f16x4*>(Yp + df * 16) = o.v;
            }
        }
    }
}

extern "C" void kernel_launch(void* const* d_in, const int* in_sizes, int n_in,
                              void* d_out, int out_size, void* d_ws, size_t ws_size,
                              hipStream_t stream) {
    const float* x  = (const float*)d_in[0];
    const float* Wa = (const float*)d_in[1];
    const float* ba = (const float*)d_in[2];
    const float* Wp = (const float*)d_in[3];
    const float* bp = (const float*)d_in[4];
    float* out = (float*)d_out;

    char* ws = (char*)d_ws;
    half_t* xh   = (half_t*)ws; ws += (size_t)NBT * NC * 2;
    half_t* Wat  = (half_t*)ws; ws += (size_t)NQKV * NC * 2;
    half_t* Wpt  = (half_t*)ws; ws += (size_t)NC * NC * 2;
    half_t* qkvh = (half_t*)ws; ws += (size_t)NBT * NQKV * 2;
    half_t* vt   = (half_t*)ws; ws += (size_t)NB * NH * ND * NT * 2;
    half_t* yh   = (half_t*)ws; ws += (size_t)NBT * NC * 2;

    k_prep<<<PREP_BLKS, 256, 0, stream>>>(x, xh, Wa, Wat, Wp, Wpt);
    k_gemm0<<<dim3(NBT / 128, NQKV / 192), 256, 0, stream>>>(xh, Wat, ba, qkvh, vt);
    k_attn<<<dim3(NT / 128, NB * NH), 256, 0, stream>>>(qkvh, vt, yh);
    k_gemm1<<<dim3(NBT / 128, NC / 96), 256, 0, stream>>>(yh, Wpt, bp, out);
}